// Round 13
// baseline (70.233 us; speedup 1.0000x reference)
//
#include <hip/hip_runtime.h>

// AttentiveConv3d: B=2, C=128, T=16, H=W=28, heads=2, HS=64, K=27 (3x3x3, pad 1)
// Round 13: TP=16 fused tile (grid 1568 -> 2x TLP vs r12) + bijective XCD
// swizzle (1568 = 8*196; halo re-reads land in the owning XCD's L2 — r8's
// failure mode was exactly this missing) + phase B reworked: thread owns
// (c0, c0+64) at one p4-group, so aw loads/addressing are shared (27 not 54).
//   K1 qfield : s[h][b][p] = sum_c q~[h,c] * x[b,c,p]              (200 KB)
//   K2 aweight: aw[b][h][k][p] softmax, OOB weights folded to 0    (5.4 MB)
//   K3 fusedmp: per 16-p tile: phase B (9-row-window merge -> LDS),
//               phase C (2co x 4p float4 projection, W via L1/L2).

#define TT 16
#define HH 28
#define WW 28
#define CC 128
#define SP (TT * HH * WW)   // 12544 = 784*16
#define NPOS (2 * SP)       // 25088
#define HS 64
#define KT 27
#define TP 16               // positions per fused tile

__global__ __launch_bounds__(256) void qfield_kernel(
    const float* __restrict__ x, const float* __restrict__ q,
    float* __restrict__ s)
{
    __shared__ float sp[16][32];     // [h*8+g][pos_local]
    const int tid = threadIdx.x;
    const int pl  = tid & 31;
    const int g   = tid >> 5;        // channel group 0..7
    const int p   = blockIdx.x * 32 + pl;
    const int b   = p / SP;
    const int si  = p % SP;
    const float* xb = x + (size_t)b * CC * SP + si;

    float acc0 = 0.f, acc1 = 0.f;    // head 0 / head 1 partials
    #pragma unroll
    for (int j = 0; j < 16; ++j) {
        const int c = g * 16 + j;              // channel
        const float val = xb[(size_t)c * SP];
        const float qv  = q[(c & 1) * HS + (c >> 1)] * (1.0f / 64.0f);
        if (c & 1) acc1 += qv * val; else acc0 += qv * val;
    }
    sp[g][pl]     = acc0;
    sp[8 + g][pl] = acc1;
    __syncthreads();
    if (tid < 64) {
        const int h = tid >> 5, pp = tid & 31;
        float a = 0.f;
        #pragma unroll
        for (int g2 = 0; g2 < 8; ++g2) a += sp[h * 8 + g2][pp];
        s[h * NPOS + blockIdx.x * 32 + pp] = a;
    }
}

// thread = (b, h, p);  aw[((b*2+h)*KT + k)*SP + p]
__global__ __launch_bounds__(256) void aweight_kernel(
    const float* __restrict__ s, float* __restrict__ aw)
{
    const int idx = blockIdx.x * 256 + threadIdx.x;   // 4*SP = 50176 exactly
    const int p = idx % SP;
    const int h = (idx / SP) & 1;
    const int b = idx / (2 * SP);
    const int v = p % WW, u = (p / WW) % HH, t = p / (WW * HH);
    const float* sf = s + h * NPOS + b * SP;

    float l[KT], msk[KT];
    #pragma unroll
    for (int k = 0; k < KT; ++k) {
        const int dt = k / 9 - 1, du = (k / 3) % 3 - 1, dv = k % 3 - 1;
        const int tt = t + dt, uu = u + du, vv = v + dv;
        const bool ok = (unsigned)tt < TT && (unsigned)uu < HH && (unsigned)vv < WW;
        l[k]   = ok ? sf[(tt * HH + uu) * WW + vv] : 0.f;  // OOB logit = 0 (pad)
        msk[k] = ok ? 1.f : 0.f;
    }
    float m = l[0];
    #pragma unroll
    for (int k = 1; k < KT; ++k) m = fmaxf(m, l[k]);
    float sum = 0.f;
    #pragma unroll
    for (int k = 0; k < KT; ++k) { l[k] = __expf(l[k] - m); sum += l[k]; }
    const float inv = 1.f / sum;
    float* awp = aw + (size_t)(b * 2 + h) * KT * SP + p;
    #pragma unroll
    for (int k = 0; k < KT; ++k)
        awp[(size_t)k * SP] = l[k] * inv * msk[k];   // OOB weight folded to 0
}

// block = 16-p tile of one batch (grid 1568 = 8 XCD x 196, swizzled).
// phase B: thread = (c0 & c0+64, one p4-group); aw shared across the 2 c's.
// phase C: cog 0..63 x vg 0..3; 2 co x 4 p (float4) per thread.
__global__ __launch_bounds__(256) void fusedmp_kernel(
    const float* __restrict__ x, const float* __restrict__ aw,
    const float* __restrict__ Wout, const float* __restrict__ bout,
    float* __restrict__ out)
{
    __shared__ float s_m[CC][TP];          // 8 KB

    // bijective XCD swizzle: 1568 = 8 * 196; bid%8 -> XCD j owns tiles
    // [j*196, (j+1)*196) — contiguous p-range, halo stays in XCD L2.
    const int pb  = (blockIdx.x & 7) * 196 + (blockIdx.x >> 3);
    const int b   = pb / (SP / TP);
    const int p0  = (pb % (SP / TP)) * TP;
    const int tid = threadIdx.x;

    // ---- phase B ----
    {
        const int c0  = tid >> 2;            // 0..63; partner channel c0+64
        const int p4g = tid & 3;
        const int p   = p0 + p4g * 4;
        const int v0  = p % WW;              // 4-aligned, never crosses a row
        const int u   = (p / WW) % HH;
        const int t   = p / (WW * HH);
        const int h   = c0 & 1;              // (c0+64)&1 == h too
        const float* xc0 = x + (size_t)(b * CC + c0) * SP;
        const float* xc1 = xc0 + (size_t)64 * SP;
        const float* awp = aw + (size_t)(b * 2 + h) * KT * SP + p;
        const int vl = (v0 == 0)  ? 0  : v0 - 1;   // clamped edges (aw=0 there)
        const int vr = (v0 == 24) ? 27 : v0 + 4;

        float4 acc0 = make_float4(0.f, 0.f, 0.f, 0.f);
        float4 acc1 = make_float4(0.f, 0.f, 0.f, 0.f);

        #pragma unroll
        for (int dt = -1; dt <= 1; ++dt) {
            #pragma unroll
            for (int du = -1; du <= 1; ++du) {
                const int tt = t + dt, uu = u + du;
                const bool rok = ((unsigned)tt < TT) && ((unsigned)uu < HH);
                const int rbase = rok ? (tt * HH + uu) * WW : 0;  // aw=0 if row OOB
                const int kb = ((dt + 1) * 3 + (du + 1)) * 3;     // k = kb + (dv+1)
                const float4 wm = *(const float4*)&awp[(size_t)(kb + 0) * SP];
                const float4 w0 = *(const float4*)&awp[(size_t)(kb + 1) * SP];
                const float4 wp = *(const float4*)&awp[(size_t)(kb + 2) * SP];
                {   // channel c0
                    const float4 a  = *(const float4*)&xc0[rbase + v0];
                    const float  xl = xc0[rbase + vl];
                    const float  xr = xc0[rbase + vr];
                    acc0.x += wm.x * xl;  acc0.y += wm.y * a.x; acc0.z += wm.z * a.y; acc0.w += wm.w * a.z;
                    acc0.x += w0.x * a.x; acc0.y += w0.y * a.y; acc0.z += w0.z * a.z; acc0.w += w0.w * a.w;
                    acc0.x += wp.x * a.y; acc0.y += wp.y * a.z; acc0.z += wp.z * a.w; acc0.w += wp.w * xr;
                }
                {   // channel c0 + 64
                    const float4 a  = *(const float4*)&xc1[rbase + v0];
                    const float  xl = xc1[rbase + vl];
                    const float  xr = xc1[rbase + vr];
                    acc1.x += wm.x * xl;  acc1.y += wm.y * a.x; acc1.z += wm.z * a.y; acc1.w += wm.w * a.z;
                    acc1.x += w0.x * a.x; acc1.y += w0.y * a.y; acc1.z += w0.z * a.z; acc1.w += w0.w * a.w;
                    acc1.x += wp.x * a.y; acc1.y += wp.y * a.z; acc1.z += wp.z * a.w; acc1.w += wp.w * xr;
                }
            }
        }
        *(float4*)&s_m[c0][p4g * 4]      = acc0;
        *(float4*)&s_m[c0 + 64][p4g * 4] = acc1;
    }
    __syncthreads();

    // ---- phase C: y[co][p] = b[co] + sum_ci W[co][ci]*merged[ci][p] ----
    const int cog = tid >> 2;              // 0..63, co = cog*2 + {0,1}
    const int vg  = tid & 3;               // p = p0 + vg*4 + vec-lane
    const float4* w0 = (const float4*)(Wout + (size_t)(cog * 2 + 0) * CC);
    const float4* w1 = (const float4*)(Wout + (size_t)(cog * 2 + 1) * CC);

    const float b0 = bout[cog * 2 + 0];
    const float b1 = bout[cog * 2 + 1];
    float4 acc0 = make_float4(b0, b0, b0, b0);
    float4 acc1 = make_float4(b1, b1, b1, b1);

    #pragma unroll 8
    for (int q4 = 0; q4 < CC / 4; ++q4) {
        const float4 wa = w0[q4];
        const float4 wb = w1[q4];
        const float4 m0 = *(const float4*)&s_m[q4 * 4 + 0][vg * 4];
        const float4 m1 = *(const float4*)&s_m[q4 * 4 + 1][vg * 4];
        const float4 m2 = *(const float4*)&s_m[q4 * 4 + 2][vg * 4];
        const float4 m3 = *(const float4*)&s_m[q4 * 4 + 3][vg * 4];
        acc0.x += wa.x * m0.x + wa.y * m1.x + wa.z * m2.x + wa.w * m3.x;
        acc0.y += wa.x * m0.y + wa.y * m1.y + wa.z * m2.y + wa.w * m3.y;
        acc0.z += wa.x * m0.z + wa.y * m1.z + wa.z * m2.z + wa.w * m3.z;
        acc0.w += wa.x * m0.w + wa.y * m1.w + wa.z * m2.w + wa.w * m3.w;
        acc1.x += wb.x * m0.x + wb.y * m1.x + wb.z * m2.x + wb.w * m3.x;
        acc1.y += wb.x * m0.y + wb.y * m1.y + wb.z * m2.y + wb.w * m3.y;
        acc1.z += wb.x * m0.z + wb.y * m1.z + wb.z * m2.z + wb.w * m3.z;
        acc1.w += wb.x * m0.w + wb.y * m1.w + wb.z * m2.w + wb.w * m3.w;
    }

    const size_t ob = (size_t)b * CC * SP + p0 + vg * 4;
    *(float4*)&out[ob + (size_t)(cog * 2 + 0) * SP] = acc0;
    *(float4*)&out[ob + (size_t)(cog * 2 + 1) * SP] = acc1;
}

extern "C" void kernel_launch(void* const* d_in, const int* in_sizes, int n_in,
                              void* d_out, int out_size, void* d_ws, size_t ws_size,
                              hipStream_t stream) {
    const float* x    = (const float*)d_in[0];
    const float* q    = (const float*)d_in[1];
    const float* Wout = (const float*)d_in[2];
    const float* bout = (const float*)d_in[3];
    float* out = (float*)d_out;

    float* s  = (float*)d_ws;                        // 50176 floats
    float* aw = s + NPOS;                            // 4*27*SP floats

    qfield_kernel <<<dim3(NPOS / 32),     dim3(256), 0, stream>>>(x, q, s);
    aweight_kernel<<<dim3(4 * SP / 256),  dim3(256), 0, stream>>>(s, aw);
    fusedmp_kernel<<<dim3(2 * (SP / TP)), dim3(256), 0, stream>>>(x, aw, Wout, bout, out);
}

// Round 14
// 50.672 us; speedup vs baseline: 1.3860x; 1.3860x over previous
//
#include <hip/hip_runtime.h>

// AttentiveConv3d: B=2, C=128, T=16, H=W=28, heads=2, HS=64, K=27 (3x3x3, pad 1)
// Round 14: r12 base (TP=32, XCD swizzle, 52us) with phase C moved to MFMA.
//   K0 wprep  : Wout -> bf16 Wb (row-major [co][ci])
//   K1 qfield : s[h][b][p] = sum_c q~[h,c] * x[b,c,p]
//   K2 aweight: aw[b][h][k][p] softmax, OOB weights folded to 0
//   K3 fusedmp: phase B (9-row-window merge, f32) -> s_mt bf16 [p][ci] LDS;
//               phase C: D = Wb @ s_mt^T via mfma_f32_16x16x32_bf16
//               (r10 zgemm fragment package, refcheck-proven), bias in C-init.

#define TT 16
#define HH 28
#define WW 28
#define CC 128
#define SP (TT * HH * WW)   // 12544 = 392*32
#define NPOS (2 * SP)       // 25088
#define HS 64
#define KT 27
#define MTS 136             // padded bf16 stride for s_mt

typedef __attribute__((ext_vector_type(8))) short bf16x8;
typedef __attribute__((ext_vector_type(4))) float f32x4;

__device__ __forceinline__ unsigned short bf16_rtne(float f) {
    unsigned u = __float_as_uint(f);
    unsigned r = (u + 0x7FFFu + ((u >> 16) & 1u)) >> 16;
    return (unsigned short)r;
}

__global__ __launch_bounds__(256) void wprep_kernel(
    const float* __restrict__ Wout, unsigned short* __restrict__ Wb)
{
    const int i = blockIdx.x * 256 + threadIdx.x;   // 16384
    Wb[i] = bf16_rtne(Wout[i]);
}

__global__ __launch_bounds__(256) void qfield_kernel(
    const float* __restrict__ x, const float* __restrict__ q,
    float* __restrict__ s)
{
    __shared__ float sp[16][32];
    const int tid = threadIdx.x;
    const int pl  = tid & 31;
    const int g   = tid >> 5;
    const int p   = blockIdx.x * 32 + pl;
    const int b   = p / SP;
    const int si  = p % SP;
    const float* xb = x + (size_t)b * CC * SP + si;

    float acc0 = 0.f, acc1 = 0.f;
    #pragma unroll
    for (int j = 0; j < 16; ++j) {
        const int c = g * 16 + j;
        const float val = xb[(size_t)c * SP];
        const float qv  = q[(c & 1) * HS + (c >> 1)] * (1.0f / 64.0f);
        if (c & 1) acc1 += qv * val; else acc0 += qv * val;
    }
    sp[g][pl]     = acc0;
    sp[8 + g][pl] = acc1;
    __syncthreads();
    if (tid < 64) {
        const int h = tid >> 5, pp = tid & 31;
        float a = 0.f;
        #pragma unroll
        for (int g2 = 0; g2 < 8; ++g2) a += sp[h * 8 + g2][pp];
        s[h * NPOS + blockIdx.x * 32 + pp] = a;
    }
}

__global__ __launch_bounds__(256) void aweight_kernel(
    const float* __restrict__ s, float* __restrict__ aw)
{
    const int idx = blockIdx.x * 256 + threadIdx.x;   // 4*SP
    const int p = idx % SP;
    const int h = (idx / SP) & 1;
    const int b = idx / (2 * SP);
    const int v = p % WW, u = (p / WW) % HH, t = p / (WW * HH);
    const float* sf = s + h * NPOS + b * SP;

    float l[KT], msk[KT];
    #pragma unroll
    for (int k = 0; k < KT; ++k) {
        const int dt = k / 9 - 1, du = (k / 3) % 3 - 1, dv = k % 3 - 1;
        const int tt = t + dt, uu = u + du, vv = v + dv;
        const bool ok = (unsigned)tt < TT && (unsigned)uu < HH && (unsigned)vv < WW;
        l[k]   = ok ? sf[(tt * HH + uu) * WW + vv] : 0.f;
        msk[k] = ok ? 1.f : 0.f;
    }
    float m = l[0];
    #pragma unroll
    for (int k = 1; k < KT; ++k) m = fmaxf(m, l[k]);
    float sum = 0.f;
    #pragma unroll
    for (int k = 0; k < KT; ++k) { l[k] = __expf(l[k] - m); sum += l[k]; }
    const float inv = 1.f / sum;
    float* awp = aw + (size_t)(b * 2 + h) * KT * SP + p;
    #pragma unroll
    for (int k = 0; k < KT; ++k)
        awp[(size_t)k * SP] = l[k] * inv * msk[k];
}

// block = 32-p tile (grid 784 = 8 XCD x 98, swizzled), 256 threads / 4 waves.
__global__ __launch_bounds__(256) void fusedmp_kernel(
    const float* __restrict__ x, const float* __restrict__ aw,
    const unsigned short* __restrict__ Wb, const float* __restrict__ bout,
    float* __restrict__ out)
{
    __shared__ unsigned short s_mt[32][MTS];   // [p_local][ci] bf16, 8.5 KB

    const int pb  = (blockIdx.x & 7) * 98 + (blockIdx.x >> 3);
    const int b   = pb / (SP / 32);
    const int p0  = (pb % (SP / 32)) * 32;
    const int tid = threadIdx.x;

    // ---- phase B: 1024 float4-tasks (c x 8 p4-groups), 4 per thread ----
    #pragma unroll
    for (int it = 0; it < 4; ++it) {
        const int task = it * 256 + tid;   // 0..1023
        const int c    = task >> 3;
        const int p4g  = task & 7;
        const int p    = p0 + p4g * 4;
        const int v0   = p % WW;           // 4-aligned, never crosses a row
        const int u    = (p / WW) % HH;
        const int t    = p / (WW * HH);
        const int h    = c & 1;
        const float* xc  = x + (size_t)(b * CC + c) * SP;
        const float* awp = aw + (size_t)(b * 2 + h) * KT * SP + p;
        const int vl = (v0 == 0)  ? 0  : v0 - 1;   // clamped edges (aw=0 there)
        const int vr = (v0 == 24) ? 27 : v0 + 4;

        float4 acc = make_float4(0.f, 0.f, 0.f, 0.f);
        #pragma unroll
        for (int dt = -1; dt <= 1; ++dt) {
            #pragma unroll
            for (int du = -1; du <= 1; ++du) {
                const int tt = t + dt, uu = u + du;
                const bool rok = ((unsigned)tt < TT) && ((unsigned)uu < HH);
                const int rbase = rok ? (tt * HH + uu) * WW : 0;  // aw=0 if row OOB
                const float4 a  = *(const float4*)&xc[rbase + v0];
                const float  xl = xc[rbase + vl];
                const float  xr = xc[rbase + vr];
                const int kb = ((dt + 1) * 3 + (du + 1)) * 3;     // k = kb + (dv+1)
                const float4 wm = *(const float4*)&awp[(size_t)(kb + 0) * SP];
                const float4 w0 = *(const float4*)&awp[(size_t)(kb + 1) * SP];
                const float4 wp = *(const float4*)&awp[(size_t)(kb + 2) * SP];
                acc.x += wm.x * xl;  acc.y += wm.y * a.x; acc.z += wm.z * a.y; acc.w += wm.w * a.z;
                acc.x += w0.x * a.x; acc.y += w0.y * a.y; acc.z += w0.z * a.z; acc.w += w0.w * a.w;
                acc.x += wp.x * a.y; acc.y += wp.y * a.z; acc.z += wp.z * a.w; acc.w += wp.w * xr;
            }
        }
        // transposed bf16 store: rows = p_local, cols = ci
        s_mt[p4g * 4 + 0][c] = bf16_rtne(acc.x);
        s_mt[p4g * 4 + 1][c] = bf16_rtne(acc.y);
        s_mt[p4g * 4 + 2][c] = bf16_rtne(acc.z);
        s_mt[p4g * 4 + 3][c] = bf16_rtne(acc.w);
    }
    __syncthreads();

    // ---- phase C: out = Wb @ merged via MFMA (r10 zgemm package) ----
    // wave w owns co-tiles {2w, 2w+1}; per cot: pt in {0,1}, ks in {0..3}.
    const int w    = tid >> 6;
    const int lane = tid & 63;
    const int lr   = lane & 15;
    const int lk   = lane >> 4;

    #pragma unroll
    for (int ci2 = 0; ci2 < 2; ++ci2) {
        const int cot = w * 2 + ci2;
        const int cob = cot * 16 + lk * 4;       // D row base for this lane
        f32x4 acc0, acc1;                        // pt = 0, 1
        #pragma unroll
        for (int r = 0; r < 4; ++r) { acc0[r] = bout[cob + r]; acc1[r] = acc0[r]; }

        #pragma unroll
        for (int ks = 0; ks < 4; ++ks) {
            const bf16x8 aA = *(const bf16x8*)&Wb[(size_t)(cot * 16 + lr) * CC + ks * 32 + lk * 8];
            const bf16x8 b0 = *(const bf16x8*)&s_mt[lr     ][ks * 32 + lk * 8];
            const bf16x8 b1 = *(const bf16x8*)&s_mt[16 + lr][ks * 32 + lk * 8];
            acc0 = __builtin_amdgcn_mfma_f32_16x16x32_bf16(aA, b0, acc0, 0, 0, 0);
            acc1 = __builtin_amdgcn_mfma_f32_16x16x32_bf16(aA, b1, acc1, 0, 0, 0);
        }
        const size_t ob = (size_t)b * CC * SP + p0;
        #pragma unroll
        for (int r = 0; r < 4; ++r) {
            out[ob + (size_t)(cob + r) * SP + lr]      = acc0[r];
            out[ob + (size_t)(cob + r) * SP + 16 + lr] = acc1[r];
        }
    }
}

extern "C" void kernel_launch(void* const* d_in, const int* in_sizes, int n_in,
                              void* d_out, int out_size, void* d_ws, size_t ws_size,
                              hipStream_t stream) {
    const float* x    = (const float*)d_in[0];
    const float* q    = (const float*)d_in[1];
    const float* Wout = (const float*)d_in[2];
    const float* bout = (const float*)d_in[3];
    float* out = (float*)d_out;

    float* s  = (float*)d_ws;                            // 25088 f32
    float* aw = s + NPOS;                                // 4*27*SP f32
    unsigned short* Wb = (unsigned short*)(aw + (size_t)4 * KT * SP);  // 16384 u16

    wprep_kernel  <<<dim3(CC * CC / 256), dim3(256), 0, stream>>>(Wout, Wb);
    qfield_kernel <<<dim3(NPOS / 32),     dim3(256), 0, stream>>>(x, q, s);
    aweight_kernel<<<dim3(4 * SP / 256),  dim3(256), 0, stream>>>(s, aw);
    fusedmp_kernel<<<dim3(2 * (SP / 32)), dim3(256), 0, stream>>>(x, aw, Wb, bout, out);
}

// Round 15
// 48.262 us; speedup vs baseline: 1.4552x; 1.0499x over previous
//
#include <hip/hip_runtime.h>

// AttentiveConv3d: B=2, C=128, T=16, H=W=28, heads=2, HS=64, K=27 (3x3x3, pad 1)
// Round 15: r14 base (50.7us) + phase B 4-channel grouping: channels
// {cg, cg+32, cg+64, cg+96} share parity -> same head -> the 27 aw float4
// loads are hoisted once per thread (VMEM instrs 216 -> 135, -37%).
// wprep folded into aweight launch (one fewer dispatch).
//   K1 qfield : s[h][b][p] = sum_c q~[h,c] * x[b,c,p]
//   K2 awwprep: blocks 0..195 aweight softmax; blocks 196..259 W->bf16
//   K3 fusedmp: phase B (merge, 4ch/thread) -> s_mt bf16 [p][ci] LDS;
//               phase C: D = Wb @ s_mt^T via mfma_f32_16x16x32_bf16.

#define TT 16
#define HH 28
#define WW 28
#define CC 128
#define SP (TT * HH * WW)   // 12544 = 392*32
#define NPOS (2 * SP)       // 25088
#define HS 64
#define KT 27
#define MTS 136             // padded bf16 stride for s_mt

typedef __attribute__((ext_vector_type(8))) short bf16x8;
typedef __attribute__((ext_vector_type(4))) float f32x4;

__device__ __forceinline__ unsigned short bf16_rtne(float f) {
    unsigned u = __float_as_uint(f);
    unsigned r = (u + 0x7FFFu + ((u >> 16) & 1u)) >> 16;
    return (unsigned short)r;
}

__global__ __launch_bounds__(256) void qfield_kernel(
    const float* __restrict__ x, const float* __restrict__ q,
    float* __restrict__ s)
{
    __shared__ float sp[16][32];
    const int tid = threadIdx.x;
    const int pl  = tid & 31;
    const int g   = tid >> 5;
    const int p   = blockIdx.x * 32 + pl;
    const int b   = p / SP;
    const int si  = p % SP;
    const float* xb = x + (size_t)b * CC * SP + si;

    float acc0 = 0.f, acc1 = 0.f;
    #pragma unroll
    for (int j = 0; j < 16; ++j) {
        const int c = g * 16 + j;
        const float val = xb[(size_t)c * SP];
        const float qv  = q[(c & 1) * HS + (c >> 1)] * (1.0f / 64.0f);
        if (c & 1) acc1 += qv * val; else acc0 += qv * val;
    }
    sp[g][pl]     = acc0;
    sp[8 + g][pl] = acc1;
    __syncthreads();
    if (tid < 64) {
        const int h = tid >> 5, pp = tid & 31;
        float a = 0.f;
        #pragma unroll
        for (int g2 = 0; g2 < 8; ++g2) a += sp[h * 8 + g2][pp];
        s[h * NPOS + blockIdx.x * 32 + pp] = a;
    }
}

// blocks 0..195: aweight; blocks 196..259: Wout -> bf16
__global__ __launch_bounds__(256) void awwprep_kernel(
    const float* __restrict__ s, float* __restrict__ aw,
    const float* __restrict__ Wout, unsigned short* __restrict__ Wb)
{
    if (blockIdx.x >= 196) {
        const int i = (blockIdx.x - 196) * 256 + threadIdx.x;   // 16384
        Wb[i] = bf16_rtne(Wout[i]);
        return;
    }
    const int idx = blockIdx.x * 256 + threadIdx.x;   // 4*SP = 50176
    const int p = idx % SP;
    const int h = (idx / SP) & 1;
    const int b = idx / (2 * SP);
    const int v = p % WW, u = (p / WW) % HH, t = p / (WW * HH);
    const float* sf = s + h * NPOS + b * SP;

    float l[KT], msk[KT];
    #pragma unroll
    for (int k = 0; k < KT; ++k) {
        const int dt = k / 9 - 1, du = (k / 3) % 3 - 1, dv = k % 3 - 1;
        const int tt = t + dt, uu = u + du, vv = v + dv;
        const bool ok = (unsigned)tt < TT && (unsigned)uu < HH && (unsigned)vv < WW;
        l[k]   = ok ? sf[(tt * HH + uu) * WW + vv] : 0.f;
        msk[k] = ok ? 1.f : 0.f;
    }
    float m = l[0];
    #pragma unroll
    for (int k = 1; k < KT; ++k) m = fmaxf(m, l[k]);
    float sum = 0.f;
    #pragma unroll
    for (int k = 0; k < KT; ++k) { l[k] = __expf(l[k] - m); sum += l[k]; }
    const float inv = 1.f / sum;
    float* awp = aw + (size_t)(b * 2 + h) * KT * SP + p;
    #pragma unroll
    for (int k = 0; k < KT; ++k)
        awp[(size_t)k * SP] = l[k] * inv * msk[k];
}

// block = 32-p tile (grid 784 = 8 XCD x 98, swizzled), 256 threads / 4 waves.
__global__ __launch_bounds__(256) void fusedmp_kernel(
    const float* __restrict__ x, const float* __restrict__ aw,
    const unsigned short* __restrict__ Wb, const float* __restrict__ bout,
    float* __restrict__ out)
{
    __shared__ unsigned short s_mt[32][MTS];   // [p_local][ci] bf16, 8.5 KB

    const int pb  = (blockIdx.x & 7) * 98 + (blockIdx.x >> 3);
    const int b   = pb / (SP / 32);
    const int p0  = (pb % (SP / 32)) * 32;
    const int tid = threadIdx.x;

    // ---- phase B: one task/thread = (cg, p4g); channels cg+32i share aw ----
    {
        const int cg  = tid >> 3;          // 0..31
        const int p4g = tid & 7;
        const int p   = p0 + p4g * 4;
        const int v0  = p % WW;            // 4-aligned, never crosses a row
        const int u   = (p / WW) % HH;
        const int t   = p / (WW * HH);
        const int h   = cg & 1;            // all 4 channels share this parity
        const float* awp = aw + (size_t)(b * 2 + h) * KT * SP + p;
        const float* xc0 = x + (size_t)(b * CC + cg) * SP;
        const int vl = (v0 == 0)  ? 0  : v0 - 1;   // clamped edges (aw=0 there)
        const int vr = (v0 == 24) ? 27 : v0 + 4;

        float4 acc[4] = { make_float4(0.f,0.f,0.f,0.f), make_float4(0.f,0.f,0.f,0.f),
                          make_float4(0.f,0.f,0.f,0.f), make_float4(0.f,0.f,0.f,0.f) };

        #pragma unroll
        for (int dt = -1; dt <= 1; ++dt) {
            #pragma unroll
            for (int du = -1; du <= 1; ++du) {
                const int tt = t + dt, uu = u + du;
                const bool rok = ((unsigned)tt < TT) && ((unsigned)uu < HH);
                const int rbase = rok ? (tt * HH + uu) * WW : 0;  // aw=0 if row OOB
                const int kb = ((dt + 1) * 3 + (du + 1)) * 3;     // k = kb + (dv+1)
                const float4 wm = *(const float4*)&awp[(size_t)(kb + 0) * SP];
                const float4 w0 = *(const float4*)&awp[(size_t)(kb + 1) * SP];
                const float4 wp = *(const float4*)&awp[(size_t)(kb + 2) * SP];
                #pragma unroll
                for (int ci = 0; ci < 4; ++ci) {
                    const float* xc = xc0 + (size_t)(32 * ci) * SP;
                    const float4 a  = *(const float4*)&xc[rbase + v0];
                    const float  xl = xc[rbase + vl];
                    const float  xr = xc[rbase + vr];
                    acc[ci].x += wm.x * xl;  acc[ci].y += wm.y * a.x;
                    acc[ci].z += wm.z * a.y; acc[ci].w += wm.w * a.z;
                    acc[ci].x += w0.x * a.x; acc[ci].y += w0.y * a.y;
                    acc[ci].z += w0.z * a.z; acc[ci].w += w0.w * a.w;
                    acc[ci].x += wp.x * a.y; acc[ci].y += wp.y * a.z;
                    acc[ci].z += wp.z * a.w; acc[ci].w += wp.w * xr;
                }
            }
        }
        #pragma unroll
        for (int ci = 0; ci < 4; ++ci) {
            const int c = cg + 32 * ci;
            s_mt[p4g * 4 + 0][c] = bf16_rtne(acc[ci].x);
            s_mt[p4g * 4 + 1][c] = bf16_rtne(acc[ci].y);
            s_mt[p4g * 4 + 2][c] = bf16_rtne(acc[ci].z);
            s_mt[p4g * 4 + 3][c] = bf16_rtne(acc[ci].w);
        }
    }
    __syncthreads();

    // ---- phase C: out = Wb @ merged via MFMA (r10 zgemm package) ----
    const int w    = tid >> 6;
    const int lane = tid & 63;
    const int lr   = lane & 15;
    const int lk   = lane >> 4;

    #pragma unroll
    for (int ci2 = 0; ci2 < 2; ++ci2) {
        const int cot = w * 2 + ci2;
        const int cob = cot * 16 + lk * 4;       // D row base for this lane
        f32x4 acc0, acc1;                        // pt = 0, 1
        #pragma unroll
        for (int r = 0; r < 4; ++r) { acc0[r] = bout[cob + r]; acc1[r] = acc0[r]; }

        #pragma unroll
        for (int ks = 0; ks < 4; ++ks) {
            const bf16x8 aA = *(const bf16x8*)&Wb[(size_t)(cot * 16 + lr) * CC + ks * 32 + lk * 8];
            const bf16x8 b0 = *(const bf16x8*)&s_mt[lr     ][ks * 32 + lk * 8];
            const bf16x8 b1 = *(const bf16x8*)&s_mt[16 + lr][ks * 32 + lk * 8];
            acc0 = __builtin_amdgcn_mfma_f32_16x16x32_bf16(aA, b0, acc0, 0, 0, 0);
            acc1 = __builtin_amdgcn_mfma_f32_16x16x32_bf16(aA, b1, acc1, 0, 0, 0);
        }
        const size_t ob = (size_t)b * CC * SP + p0;
        #pragma unroll
        for (int r = 0; r < 4; ++r) {
            out[ob + (size_t)(cob + r) * SP + lr]      = acc0[r];
            out[ob + (size_t)(cob + r) * SP + 16 + lr] = acc1[r];
        }
    }
}

extern "C" void kernel_launch(void* const* d_in, const int* in_sizes, int n_in,
                              void* d_out, int out_size, void* d_ws, size_t ws_size,
                              hipStream_t stream) {
    const float* x    = (const float*)d_in[0];
    const float* q    = (const float*)d_in[1];
    const float* Wout = (const float*)d_in[2];
    const float* bout = (const float*)d_in[3];
    float* out = (float*)d_out;

    float* s  = (float*)d_ws;                            // 25088 f32
    float* aw = s + NPOS;                                // 4*27*SP f32
    unsigned short* Wb = (unsigned short*)(aw + (size_t)4 * KT * SP);  // 16384 u16

    qfield_kernel <<<dim3(NPOS / 32),     dim3(256), 0, stream>>>(x, q, s);
    awwprep_kernel<<<dim3(196 + 64),      dim3(256), 0, stream>>>(s, aw, Wout, Wb);
    fusedmp_kernel<<<dim3(2 * (SP / 32)), dim3(256), 0, stream>>>(x, aw, Wb, bout, out);
}

// Round 17
// 44.527 us; speedup vs baseline: 1.5773x; 1.0839x over previous
//
#include <hip/hip_runtime.h>

// AttentiveConv3d: B=2, C=128, T=16, H=W=28, heads=2, HS=64, K=27 (3x3x3, pad 1)
// Round 17: r16 with the workspace-aliasing bug fixed (Wb was at s+NPOS but
// s spans 2*NPOS floats -> W bf16 blocks overwrote s[h=1] -> NaN).
//   K1 qfieldw: blocks 0..783 s-field; blocks 784..847 W->bf16
//   K2 fusedmp: A) aw[2][27][32] in LDS from s-field softmax (64 thr)
//               B) 9-row-window merge (4ch/thread, aw via LDS broadcast)
//               C) D = Wb @ s_mt^T via mfma_f32_16x16x32_bf16 (+bias)

#define TT 16
#define HH 28
#define WW 28
#define CC 128
#define SP (TT * HH * WW)   // 12544 = 392*32
#define NPOS (2 * SP)       // 25088
#define HS 64
#define KT 27
#define MTS 136             // padded bf16 stride for s_mt

typedef __attribute__((ext_vector_type(8))) short bf16x8;
typedef __attribute__((ext_vector_type(4))) float f32x4;

__device__ __forceinline__ unsigned short bf16_rtne(float f) {
    unsigned u = __float_as_uint(f);
    unsigned r = (u + 0x7FFFu + ((u >> 16) & 1u)) >> 16;
    return (unsigned short)r;
}

// blocks 0..783: s[h][b][p] = sum_c q~[h,c]*x[b,c,p]; blocks 784..847: W->bf16
__global__ __launch_bounds__(256) void qfieldw_kernel(
    const float* __restrict__ x, const float* __restrict__ q,
    float* __restrict__ s,
    const float* __restrict__ Wout, unsigned short* __restrict__ Wb)
{
    if (blockIdx.x >= 784) {
        const int i = (blockIdx.x - 784) * 256 + threadIdx.x;   // 16384
        Wb[i] = bf16_rtne(Wout[i]);
        return;
    }
    __shared__ float sp[16][32];
    const int tid = threadIdx.x;
    const int pl  = tid & 31;
    const int g   = tid >> 5;
    const int p   = blockIdx.x * 32 + pl;
    const int b   = p / SP;
    const int si  = p % SP;
    const float* xb = x + (size_t)b * CC * SP + si;

    float acc0 = 0.f, acc1 = 0.f;
    #pragma unroll
    for (int j = 0; j < 16; ++j) {
        const int c = g * 16 + j;
        const float val = xb[(size_t)c * SP];
        const float qv  = q[(c & 1) * HS + (c >> 1)] * (1.0f / 64.0f);
        if (c & 1) acc1 += qv * val; else acc0 += qv * val;
    }
    sp[g][pl]     = acc0;
    sp[8 + g][pl] = acc1;
    __syncthreads();
    if (tid < 64) {
        const int h = tid >> 5, pp = tid & 31;
        float a = 0.f;
        #pragma unroll
        for (int g2 = 0; g2 < 8; ++g2) a += sp[h * 8 + g2][pp];
        s[h * NPOS + blockIdx.x * 32 + pp] = a;
    }
}

// block = 32-p tile (grid 784 = 8 XCD x 98, swizzled), 256 threads / 4 waves.
__global__ __launch_bounds__(256) void fusedmp_kernel(
    const float* __restrict__ x, const float* __restrict__ s,
    const unsigned short* __restrict__ Wb, const float* __restrict__ bout,
    float* __restrict__ out)
{
    __shared__ float s_aw[KT][2][32];          // 6.75 KB (masked attn weights)
    __shared__ unsigned short s_mt[32][MTS];   // [p_local][ci] bf16, 8.5 KB

    const int pb  = (blockIdx.x & 7) * 98 + (blockIdx.x >> 3);
    const int b   = pb / (SP / 32);
    const int p0  = (pb % (SP / 32)) * 32;
    const int tid = threadIdx.x;

    // ---- phase A: attention weights from s-field (64 threads: h x 32 p) ----
    if (tid < 64) {
        const int h  = tid >> 5;
        const int pl = tid & 31;
        const int p  = p0 + pl;
        const int v = p % WW, u = (p / WW) % HH, t = p / (WW * HH);
        const float* sf = s + h * NPOS + b * SP;
        float l[KT], msk[KT];
        #pragma unroll
        for (int k = 0; k < KT; ++k) {
            const int dt = k / 9 - 1, du = (k / 3) % 3 - 1, dv = k % 3 - 1;
            const int tt = t + dt, uu = u + du, vv = v + dv;
            const bool ok = (unsigned)tt < TT && (unsigned)uu < HH && (unsigned)vv < WW;
            l[k]   = ok ? sf[(tt * HH + uu) * WW + vv] : 0.f;  // pad logit = 0
            msk[k] = ok ? 1.f : 0.f;
        }
        float m = l[0];
        #pragma unroll
        for (int k = 1; k < KT; ++k) m = fmaxf(m, l[k]);
        float sum = 0.f;
        #pragma unroll
        for (int k = 0; k < KT; ++k) { l[k] = __expf(l[k] - m); sum += l[k]; }
        const float inv = 1.f / sum;
        #pragma unroll
        for (int k = 0; k < KT; ++k)
            s_aw[k][h][pl] = l[k] * inv * msk[k];   // OOB weight folded to 0
    }
    __syncthreads();

    // ---- phase B: one task/thread = (cg, p4g); channels cg+32i share aw ----
    {
        const int cg  = tid >> 3;          // 0..31
        const int p4g = tid & 7;
        const int p   = p0 + p4g * 4;
        const int v0  = p % WW;            // 4-aligned, never crosses a row
        const int u   = (p / WW) % HH;
        const int t   = p / (WW * HH);
        const int h   = cg & 1;            // all 4 channels share this parity
        const float* xc0 = x + (size_t)(b * CC + cg) * SP;
        const int vl = (v0 == 0)  ? 0  : v0 - 1;   // clamped edges (aw=0 there)
        const int vr = (v0 == 24) ? 27 : v0 + 4;

        float4 acc[4] = { make_float4(0.f,0.f,0.f,0.f), make_float4(0.f,0.f,0.f,0.f),
                          make_float4(0.f,0.f,0.f,0.f), make_float4(0.f,0.f,0.f,0.f) };

        #pragma unroll
        for (int dt = -1; dt <= 1; ++dt) {
            #pragma unroll
            for (int du = -1; du <= 1; ++du) {
                const int tt = t + dt, uu = u + du;
                const bool rok = ((unsigned)tt < TT) && ((unsigned)uu < HH);
                const int rbase = rok ? (tt * HH + uu) * WW : 0;  // aw=0 if row OOB
                const int kb = ((dt + 1) * 3 + (du + 1)) * 3;     // k = kb + (dv+1)
                const float4 wm = *(const float4*)&s_aw[kb + 0][h][p4g * 4];
                const float4 w0 = *(const float4*)&s_aw[kb + 1][h][p4g * 4];
                const float4 wp = *(const float4*)&s_aw[kb + 2][h][p4g * 4];
                #pragma unroll
                for (int ci = 0; ci < 4; ++ci) {
                    const float* xc = xc0 + (size_t)(32 * ci) * SP;
                    const float4 a  = *(const float4*)&xc[rbase + v0];
                    const float  xl = xc[rbase + vl];
                    const float  xr = xc[rbase + vr];
                    acc[ci].x += wm.x * xl;  acc[ci].y += wm.y * a.x;
                    acc[ci].z += wm.z * a.y; acc[ci].w += wm.w * a.z;
                    acc[ci].x += w0.x * a.x; acc[ci].y += w0.y * a.y;
                    acc[ci].z += w0.z * a.z; acc[ci].w += w0.w * a.w;
                    acc[ci].x += wp.x * a.y; acc[ci].y += wp.y * a.z;
                    acc[ci].z += wp.z * a.w; acc[ci].w += wp.w * xr;
                }
            }
        }
        #pragma unroll
        for (int ci = 0; ci < 4; ++ci) {
            const int c = cg + 32 * ci;
            s_mt[p4g * 4 + 0][c] = bf16_rtne(acc[ci].x);
            s_mt[p4g * 4 + 1][c] = bf16_rtne(acc[ci].y);
            s_mt[p4g * 4 + 2][c] = bf16_rtne(acc[ci].z);
            s_mt[p4g * 4 + 3][c] = bf16_rtne(acc[ci].w);
        }
    }
    __syncthreads();

    // ---- phase C: out = Wb @ merged via MFMA (r10 zgemm package) ----
    const int w    = tid >> 6;
    const int lane = tid & 63;
    const int lr   = lane & 15;
    const int lk   = lane >> 4;

    #pragma unroll
    for (int ci2 = 0; ci2 < 2; ++ci2) {
        const int cot = w * 2 + ci2;
        const int cob = cot * 16 + lk * 4;       // D row base for this lane
        f32x4 acc0, acc1;                        // pt = 0, 1
        #pragma unroll
        for (int r = 0; r < 4; ++r) { acc0[r] = bout[cob + r]; acc1[r] = acc0[r]; }

        #pragma unroll
        for (int ks = 0; ks < 4; ++ks) {
            const bf16x8 aA = *(const bf16x8*)&Wb[(size_t)(cot * 16 + lr) * CC + ks * 32 + lk * 8];
            const bf16x8 b0 = *(const bf16x8*)&s_mt[lr     ][ks * 32 + lk * 8];
            const bf16x8 b1 = *(const bf16x8*)&s_mt[16 + lr][ks * 32 + lk * 8];
            acc0 = __builtin_amdgcn_mfma_f32_16x16x32_bf16(aA, b0, acc0, 0, 0, 0);
            acc1 = __builtin_amdgcn_mfma_f32_16x16x32_bf16(aA, b1, acc1, 0, 0, 0);
        }
        const size_t ob = (size_t)b * CC * SP + p0;
        #pragma unroll
        for (int r = 0; r < 4; ++r) {
            out[ob + (size_t)(cob + r) * SP + lr]      = acc0[r];
            out[ob + (size_t)(cob + r) * SP + 16 + lr] = acc1[r];
        }
    }
}

extern "C" void kernel_launch(void* const* d_in, const int* in_sizes, int n_in,
                              void* d_out, int out_size, void* d_ws, size_t ws_size,
                              hipStream_t stream) {
    const float* x    = (const float*)d_in[0];
    const float* q    = (const float*)d_in[1];
    const float* Wout = (const float*)d_in[2];
    const float* bout = (const float*)d_in[3];
    float* out = (float*)d_out;

    float* s = (float*)d_ws;                                  // 2*NPOS f32
    unsigned short* Wb = (unsigned short*)(s + 2 * NPOS);     // 16384 u16, AFTER s

    qfieldw_kernel<<<dim3(784 + 64),      dim3(256), 0, stream>>>(x, q, s, Wout, Wb);
    fusedmp_kernel<<<dim3(2 * (SP / 32)), dim3(256), 0, stream>>>(x, s, Wb, bout, out);
}